// Round 11
// baseline (101.192 us; speedup 1.0000x reference)
//
#include <hip/hip_runtime.h>
#include <hip/hip_fp16.h>

// SpMM scatter-reduce: out[r] = sum_{e: rows[e]==r} vals[e] * embeds[cols[e]]
// Pipeline (5 launches, no global atomics):
//   1) count_convert: partitioned grid. Blocks [0,NWG): per-WG LDS histogram
//      over 1042 buckets (96 rows) -> bucket-major matrix cnt[b][w].
//      Blocks [NWG,..): embeds fp32 -> int8+scale, one row per wave:
//      64 B row = 48 int8 quants + fp16 scale + pad  (gather = ONE cacheline)
//   2) scan_phase1: per-block sums of 2048-entry chunks of mat
//   3) scan_phase3: apply (rescans the 131 block sums in LDS); emits bstart[]
//   4) place_kernel: LDS cursors, edges bucket-grouped into buf1 (int2)
//   5) finalize_spmm: one 512-thr WG per bucket (1042 WGs = 102% thread slots).
//      Counting-sort bucket edges into LDS (packed u32: fp16val<<17|col), then
//      row-parallel spmm: 16 groups x 32 lanes, 6 rows/group, lane = feat pair.

#define N_NODES 100000
#define N_EDGES 1600000
#define D_FEAT  48

#define RPB 96
#define NBUCKETS ((N_NODES + RPB - 1) / RPB)                    // 1042
#define NWG 256
#define CHUNK ((N_EDGES + NWG - 1) / NWG)                       // 6250
#define MAT (NBUCKETS * NWG)                                    // 266752
#define SCAN_CHUNK 2048
#define NB_SCAN ((MAT + SCAN_CHUNK - 1) / SCAN_CHUNK)           // 131
#define CONV_WGS (N_NODES / 8)                                  // 12500
#define CAP 2048   // mean 1536, sd 39 -> 13 sigma headroom

__device__ __forceinline__ unsigned bucket_of(unsigned r) {
    // r / 96, exact for r < 2^17 (magic: ceil(2^38/96) = 2863311531)
    return __umulhi(r, 2863311531u) >> 6;
}

// ---- 1) fused: per-WG bucket histogram + embeds fp32 -> int8/64B rows ----
__global__ __launch_bounds__(512) void count_convert(const int* __restrict__ rows,
                                                     unsigned int* __restrict__ mat,
                                                     const float2* __restrict__ esrc,
                                                     unsigned short* __restrict__ embq) {
    const int t = threadIdx.x;
    if (blockIdx.x < NWG) {
        __shared__ unsigned int lc[NBUCKETS];
        const int w = blockIdx.x;
        for (int i = t; i < NBUCKETS; i += 512) lc[i] = 0u;
        __syncthreads();
        const int lo = w * CHUNK;
        const int hi = (lo + CHUNK < N_EDGES) ? lo + CHUNK : N_EDGES;
        for (int e = lo + t; e < hi; e += 512)
            atomicAdd(&lc[bucket_of((unsigned)rows[e])], 1u);
        __syncthreads();
        for (int b = t; b < NBUCKETS; b += 512)
            mat[b * NWG + w] = lc[b];
    } else {
        // one row per 64-lane wave; lanes 0..23 hold a float2 (2 feats)
        const int row  = (blockIdx.x - NWG) * 8 + (t >> 6);
        const int lane = t & 63;
        float2 v = make_float2(0.f, 0.f);
        if (lane < 24) v = esrc[(size_t)row * 24 + lane];
        float m = fmaxf(fabsf(v.x), fabsf(v.y));
#pragma unroll
        for (int mask = 1; mask <= 32; mask <<= 1)
            m = fmaxf(m, __shfl_xor(m, mask));
        float inv = (m > 0.f) ? 127.f / m : 0.f;
        if (lane < 24) {
            int lo = __float2int_rn(v.x * inv);
            int hi = __float2int_rn(v.y * inv);
            unsigned short p = (unsigned short)((lo & 0xff) | ((hi & 0xff) << 8));
            embq[(size_t)row * 32 + lane] = p;
        }
        if (lane == 24)
            embq[(size_t)row * 32 + 24] = __half_as_ushort(__float2half(m * (1.f / 127.f)));
        // bytes 50..63 of the row are never read; leave as-is
    }
}

// ---- 2) per-block sums (2048 entries/block) ----
__global__ __launch_bounds__(256) void scan_phase1(const unsigned int* __restrict__ mat,
                                                   unsigned int* __restrict__ bsum) {
    __shared__ unsigned int s[256];
    const int blk = blockIdx.x, t = threadIdx.x;
    const int base = blk * SCAN_CHUNK + t * 8;
    unsigned int sum = 0;
#pragma unroll
    for (int k = 0; k < 8; ++k) {
        int i = base + k;
        if (i < MAT) sum += mat[i];
    }
    s[t] = sum;
    __syncthreads();
    for (int off = 128; off > 0; off >>= 1) {
        if (t < off) s[t] += s[t + off];
        __syncthreads();
    }
    if (t == 0) bsum[blk] = s[0];
}

// ---- 3) apply (each block rescans all 131 block sums locally) ----
__global__ __launch_bounds__(256) void scan_phase3(unsigned int* __restrict__ mat,
                                                   const unsigned int* __restrict__ bsum,
                                                   unsigned int* __restrict__ bstart) {
    __shared__ unsigned int s[256];
    __shared__ unsigned int bpre[256];
    const int blk = blockIdx.x, t = threadIdx.x;
    bpre[t] = (t < NB_SCAN) ? bsum[t] : 0u;
    __syncthreads();
    for (int off = 1; off < 256; off <<= 1) {
        unsigned int u = (t >= off) ? bpre[t - off] : 0u;
        __syncthreads();
        bpre[t] += u;
        __syncthreads();
    }
    const unsigned int blkbase = (blk == 0) ? 0u : bpre[blk - 1];

    const int base = blk * SCAN_CHUNK + t * 8;
    unsigned int c[8];
    unsigned int sum = 0;
#pragma unroll
    for (int k = 0; k < 8; ++k) {
        int i = base + k;
        c[k] = (i < MAT) ? mat[i] : 0u;
        sum += c[k];
    }
    s[t] = sum;
    __syncthreads();
    for (int off = 1; off < 256; off <<= 1) {
        unsigned int u = (t >= off) ? s[t - off] : 0u;
        __syncthreads();
        s[t] += u;
        __syncthreads();
    }
    unsigned int prefix = blkbase + ((t == 0) ? 0u : s[t - 1]);
#pragma unroll
    for (int k = 0; k < 8; ++k) {
        int i = base + k;
        if (i < MAT) {
            mat[i] = prefix;
            if ((i & (NWG - 1)) == 0) bstart[i >> 8] = prefix;
            prefix += c[k];
        }
    }
    if (blk == 0 && t == 0) bstart[NBUCKETS] = N_EDGES;
}

// ---- 4) placement: LDS cursors only; each WG owns its runs ----
__global__ __launch_bounds__(512) void place_kernel(const int* __restrict__ rows,
                                                    const int* __restrict__ cols,
                                                    const float* __restrict__ vals,
                                                    const unsigned int* __restrict__ mat,
                                                    int2* __restrict__ buf1) {
    __shared__ unsigned int lc[NBUCKETS];
    const int w = blockIdx.x, t = threadIdx.x;
    for (int b = t; b < NBUCKETS; b += 512) lc[b] = mat[b * NWG + w];
    __syncthreads();
    const int lo = w * CHUNK;
    const int hi = (lo + CHUNK < N_EDGES) ? lo + CHUNK : N_EDGES;
    for (int e = lo + t; e < hi; e += 512) {
        unsigned r = (unsigned)rows[e];
        unsigned b = bucket_of(r);
        unsigned lr = r - b * RPB;                       // < 96, fits 7 bits
        unsigned int pos = atomicAdd(&lc[b], 1u);        // LDS atomic only
        buf1[pos] = make_int2((int)((lr << 17) | (unsigned)cols[e]),
                              __float_as_int(vals[e]));
    }
}

// ---- 5) fused per-bucket counting-sort (LDS) + row-parallel int8 spmm ----
__global__ __launch_bounds__(512) void finalize_spmm(const unsigned int* __restrict__ bstart,
                                                     const int2* __restrict__ buf1,
                                                     const unsigned short* __restrict__ embq,
                                                     float* __restrict__ out) {
    __shared__ unsigned int sedge[CAP];          // (fp16val<<17)|col, row-sorted
    __shared__ unsigned int rstart[RPB + 1];
    __shared__ unsigned int rc[RPB];
    __shared__ unsigned int sscan[RPB];
    const int b = blockIdx.x, t = threadIdx.x;
    const unsigned int S = bstart[b];
    const unsigned int E = bstart[b + 1];
    const unsigned int cnt = E - S;
    const int g   = t >> 5;        // 0..15: 16 groups, 6 rows each
    const int sub = t & 31;        // feature pair; active sub < 24
    const bool act = sub < 24;
    const int row0 = b * RPB;

#define PROC(q)                                                          \
    {                                                                    \
        unsigned col = (q) & 0x1FFFFu;                                   \
        const unsigned short* rp = embq + ((size_t)col << 5);            \
        unsigned short qq = rp[sub];                                     \
        float sc = __half2float(__ushort_as_half(rp[24]));               \
        float vs = __half2float(__ushort_as_half((unsigned short)((q) >> 17))) * sc; \
        float lo = (float)(int)(signed char)(qq & 0xff);                 \
        float hi = (float)(int)(signed char)(qq >> 8);                   \
        ax = fmaf(vs, lo, ax);                                           \
        ay = fmaf(vs, hi, ay);                                           \
    }

    if (cnt <= CAP) {
        if (t < RPB) rc[t] = 0u;
        __syncthreads();
        for (unsigned int j = S + t; j < E; j += 512)
            atomicAdd(&rc[(unsigned)buf1[j].x >> 17], 1u);
        __syncthreads();
        if (t < RPB) sscan[t] = rc[t];
        __syncthreads();
        for (int off = 1; off < RPB; off <<= 1) {
            unsigned int u = 0;
            if (t < RPB && t >= off) u = sscan[t - off];
            __syncthreads();
            if (t < RPB && t >= off) sscan[t] += u;
            __syncthreads();
        }
        if (t < RPB) {
            unsigned int pre = (t == 0) ? 0u : sscan[t - 1];
            rstart[t] = pre;
            rc[t] = pre;   // reuse as LDS scatter cursor
        }
        if (t == 0) rstart[RPB] = cnt;
        __syncthreads();
        for (unsigned int j = S + t; j < E; j += 512) {
            int2 cv = buf1[j];
            unsigned int pos = atomicAdd(&rc[(unsigned)cv.x >> 17], 1u);
            union { __half h; unsigned short u; } hv;
            hv.h = __float2half_rn(__int_as_float(cv.y));  // val>=0 -> 15 bits
            sedge[pos] = ((unsigned int)hv.u << 17) | ((unsigned)cv.x & 0x1FFFFu);
        }
        __syncthreads();

        for (int rr = g * 6; rr < g * 6 + 6; ++rr) {
            int row = row0 + rr;
            if (row >= N_NODES) break;
            unsigned int j = rstart[rr], end = rstart[rr + 1];
            float ax = 0.f, ay = 0.f;
            for (; j + 8 <= end; j += 8) {
                unsigned int q0 = sedge[j + 0];
                unsigned int q1 = sedge[j + 1];
                unsigned int q2 = sedge[j + 2];
                unsigned int q3 = sedge[j + 3];
                unsigned int q4 = sedge[j + 4];
                unsigned int q5 = sedge[j + 5];
                unsigned int q6 = sedge[j + 6];
                unsigned int q7 = sedge[j + 7];
                if (act) {
                    PROC(q0) PROC(q1) PROC(q2) PROC(q3)
                    PROC(q4) PROC(q5) PROC(q6) PROC(q7)
                }
            }
            for (; j < end; ++j) {
                unsigned int q = sedge[j];
                if (act) PROC(q)
            }
            if (act)
                *(float2*)(out + (size_t)row * D_FEAT + sub * 2) = make_float2(ax, ay);
        }
    } else {
        // capacity-overflow fallback (13-sigma event): scan global window
        for (int rr = g * 6; rr < g * 6 + 6; ++rr) {
            int row = row0 + rr;
            if (row >= N_NODES) break;
            float ax = 0.f, ay = 0.f;
            for (unsigned int j = S; j < E; ++j) {
                int2 cv = buf1[j];
                if (((unsigned)cv.x >> 17) == (unsigned)rr && act) {
                    union { __half h; unsigned short u; } hv;
                    hv.h = __float2half_rn(__int_as_float(cv.y));
                    unsigned int q = ((unsigned int)hv.u << 17) | ((unsigned)cv.x & 0x1FFFFu);
                    PROC(q)
                }
            }
            if (act)
                *(float2*)(out + (size_t)row * D_FEAT + sub * 2) = make_float2(ax, ay);
        }
    }
#undef PROC
}

// ---- fallback (tiny ws): edge-parallel global atomics ----
__global__ __launch_bounds__(256) void zero_out_kernel(float4* __restrict__ out, int n4) {
    int i = blockIdx.x * 256 + threadIdx.x;
    if (i < n4) out[i] = make_float4(0.f, 0.f, 0.f, 0.f);
}
__global__ __launch_bounds__(256) void spmm_atomic_kernel(const int* __restrict__ rows,
                                                          const int* __restrict__ cols,
                                                          const float* __restrict__ vals,
                                                          const float* __restrict__ embeds,
                                                          float* __restrict__ out) {
    long long tid = (long long)blockIdx.x * 256 + threadIdx.x;
    const long long total = (long long)N_EDGES * 12;
    if (tid >= total) return;
    int e = (int)(tid / 12), q = (int)(tid % 12);
    int r = rows[e], c = cols[e];
    float v = vals[e];
    const float4 emb = *(const float4*)(embeds + (long long)c * D_FEAT + q * 4);
    float* o = out + (long long)r * D_FEAT + q * 4;
    atomicAdd(o + 0, v * emb.x);
    atomicAdd(o + 1, v * emb.y);
    atomicAdd(o + 2, v * emb.z);
    atomicAdd(o + 3, v * emb.w);
}

extern "C" void kernel_launch(void* const* d_in, const int* in_sizes, int n_in,
                              void* d_out, int out_size, void* d_ws, size_t ws_size,
                              hipStream_t stream) {
    const int*   rows   = (const int*)d_in[0];
    const int*   cols   = (const int*)d_in[1];
    const float* vals   = (const float*)d_in[2];
    const float* embeds = (const float*)d_in[3];
    float*       out    = (float*)d_out;

    // workspace layout (~20.3 MB):
    //   mat: MAT u32 | bstart: NBUCKETS+1 | bsum: NB_SCAN | buf1: E int2 |
    //   embq: N * 64 B (int8 rows + fp16 scale)
    unsigned int* mat = (unsigned int*)d_ws;
    size_t mat_bytes  = ((size_t)MAT * 4 + 15) & ~(size_t)15;
    unsigned int* bstart = (unsigned int*)((char*)d_ws + mat_bytes);
    size_t bs_bytes   = (((size_t)(NBUCKETS + 1) * 4) + 15) & ~(size_t)15;
    unsigned int* bsum = (unsigned int*)((char*)d_ws + mat_bytes + bs_bytes);
    size_t bsum_bytes = (((size_t)NB_SCAN * 4) + 15) & ~(size_t)15;
    int2* buf1 = (int2*)((char*)d_ws + mat_bytes + bs_bytes + bsum_bytes);
    unsigned short* embq = (unsigned short*)((char*)buf1 + (size_t)N_EDGES * 8);
    size_t need = mat_bytes + bs_bytes + bsum_bytes +
                  (size_t)N_EDGES * 8 + (size_t)N_NODES * 64;

    if (ws_size < need) {
        int n4 = out_size / 4;
        zero_out_kernel<<<(n4 + 255) / 256, 256, 0, stream>>>((float4*)out, n4);
        long long total = (long long)N_EDGES * 12;
        spmm_atomic_kernel<<<(int)((total + 255) / 256), 256, 0, stream>>>(rows, cols, vals, embeds, out);
        return;
    }

    count_convert<<<NWG + CONV_WGS, 512, 0, stream>>>(rows, mat,
                                                      (const float2*)embeds, embq);
    scan_phase1<<<NB_SCAN, 256, 0, stream>>>(mat, bsum);
    scan_phase3<<<NB_SCAN, 256, 0, stream>>>(mat, bsum, bstart);
    place_kernel<<<NWG, 512, 0, stream>>>(rows, cols, vals, mat, buf1);
    finalize_spmm<<<NBUCKETS, 512, 0, stream>>>(bstart, buf1, embq, out);
}

// Round 12
// 86.967 us; speedup vs baseline: 1.1636x; 1.1636x over previous
//
#include <hip/hip_runtime.h>
#include <hip/hip_fp16.h>

// SpMM scatter-reduce: out[r] = sum_{e: rows[e]==r} vals[e] * embeds[cols[e]]
// Pipeline (5 launches, no global atomics):
//   1) count_convert: partitioned grid. Blocks [0,NWG): per-WG LDS histogram
//      over 1563 buckets (64 rows) -> bucket-major matrix cnt[b][w].
//      Blocks [NWG,..): embeds fp32 -> fp16 (float4 -> 2x half2).
//   2) scan_phase1: per-block sums of 2048-entry chunks of mat
//   3) scan_phase3: apply (rescans the 196 block sums in LDS); emits bstart[]
//   4) place_kernel: LDS cursors, edges bucket-grouped into buf1 (int2)
//   5) finalize_spmm: one 512-thr WG per bucket (1563 WGs = 6.1/CU).
//      Counting-sort bucket edges into LDS (packed u32: fp16val<<17|col), then
//      row-parallel spmm: 16 groups x 32 lanes, 4 rows/group, lane = half2
//      feature pair, x8 gather ILP.

#define N_NODES 100000
#define N_EDGES 1600000
#define D_FEAT  48

#define RPB 64
#define NBUCKETS ((N_NODES + RPB - 1) / RPB)                    // 1563
#define NWG 256
#define CHUNK ((N_EDGES + NWG - 1) / NWG)                       // 6250
#define MAT (NBUCKETS * NWG)                                    // 400128
#define SCAN_CHUNK 2048
#define NB_SCAN ((MAT + SCAN_CHUNK - 1) / SCAN_CHUNK)           // 196
#define CONV_N4 ((N_NODES * D_FEAT) / 4)                        // 1200000
#define CONV_BLK ((CONV_N4 + 511) / 512)                        // 2344
#define CAP 1536   // mean 1024, sd ~32 -> 16 sigma headroom

// ---- 1) fused: per-WG bucket histogram + embeds fp32 -> fp16 ----
__global__ __launch_bounds__(512) void count_convert(const int* __restrict__ rows,
                                                     unsigned int* __restrict__ mat,
                                                     const float4* __restrict__ esrc,
                                                     __half2* __restrict__ edst) {
    const int t = threadIdx.x;
    if (blockIdx.x < NWG) {
        __shared__ unsigned int lc[NBUCKETS];
        const int w = blockIdx.x;
        for (int i = t; i < NBUCKETS; i += 512) lc[i] = 0u;
        __syncthreads();
        const int lo = w * CHUNK;
        const int hi = (lo + CHUNK < N_EDGES) ? lo + CHUNK : N_EDGES;
        for (int e = lo + t; e < hi; e += 512)
            atomicAdd(&lc[((unsigned)rows[e]) >> 6], 1u);
        __syncthreads();
        for (int b = t; b < NBUCKETS; b += 512)
            mat[b * NWG + w] = lc[b];
    } else {
        int i = (blockIdx.x - NWG) * 512 + t;
        if (i < CONV_N4) {
            float4 v = esrc[i];
            edst[2 * i]     = __floats2half2_rn(v.x, v.y);
            edst[2 * i + 1] = __floats2half2_rn(v.z, v.w);
        }
    }
}

// ---- 2) per-block sums (2048 entries/block) ----
__global__ __launch_bounds__(256) void scan_phase1(const unsigned int* __restrict__ mat,
                                                   unsigned int* __restrict__ bsum) {
    __shared__ unsigned int s[256];
    const int blk = blockIdx.x, t = threadIdx.x;
    const int base = blk * SCAN_CHUNK + t * 8;
    unsigned int sum = 0;
#pragma unroll
    for (int k = 0; k < 8; ++k) {
        int i = base + k;
        if (i < MAT) sum += mat[i];
    }
    s[t] = sum;
    __syncthreads();
    for (int off = 128; off > 0; off >>= 1) {
        if (t < off) s[t] += s[t + off];
        __syncthreads();
    }
    if (t == 0) bsum[blk] = s[0];
}

// ---- 3) apply (each block rescans all 196 block sums locally) ----
__global__ __launch_bounds__(256) void scan_phase3(unsigned int* __restrict__ mat,
                                                   const unsigned int* __restrict__ bsum,
                                                   unsigned int* __restrict__ bstart) {
    __shared__ unsigned int s[256];
    __shared__ unsigned int bpre[256];
    const int blk = blockIdx.x, t = threadIdx.x;
    bpre[t] = (t < NB_SCAN) ? bsum[t] : 0u;
    __syncthreads();
    for (int off = 1; off < 256; off <<= 1) {
        unsigned int u = (t >= off) ? bpre[t - off] : 0u;
        __syncthreads();
        bpre[t] += u;
        __syncthreads();
    }
    const unsigned int blkbase = (blk == 0) ? 0u : bpre[blk - 1];

    const int base = blk * SCAN_CHUNK + t * 8;
    unsigned int c[8];
    unsigned int sum = 0;
#pragma unroll
    for (int k = 0; k < 8; ++k) {
        int i = base + k;
        c[k] = (i < MAT) ? mat[i] : 0u;
        sum += c[k];
    }
    s[t] = sum;
    __syncthreads();
    for (int off = 1; off < 256; off <<= 1) {
        unsigned int u = (t >= off) ? s[t - off] : 0u;
        __syncthreads();
        s[t] += u;
        __syncthreads();
    }
    unsigned int prefix = blkbase + ((t == 0) ? 0u : s[t - 1]);
#pragma unroll
    for (int k = 0; k < 8; ++k) {
        int i = base + k;
        if (i < MAT) {
            mat[i] = prefix;
            if ((i & (NWG - 1)) == 0) bstart[i >> 8] = prefix;
            prefix += c[k];
        }
    }
    if (blk == 0 && t == 0) bstart[NBUCKETS] = N_EDGES;
}

// ---- 4) placement: LDS cursors only; each WG owns its runs ----
__global__ __launch_bounds__(512) void place_kernel(const int* __restrict__ rows,
                                                    const int* __restrict__ cols,
                                                    const float* __restrict__ vals,
                                                    const unsigned int* __restrict__ mat,
                                                    int2* __restrict__ buf1) {
    __shared__ unsigned int lc[NBUCKETS];
    const int w = blockIdx.x, t = threadIdx.x;
    for (int b = t; b < NBUCKETS; b += 512) lc[b] = mat[b * NWG + w];
    __syncthreads();
    const int lo = w * CHUNK;
    const int hi = (lo + CHUNK < N_EDGES) ? lo + CHUNK : N_EDGES;
    for (int e = lo + t; e < hi; e += 512) {
        unsigned r = (unsigned)rows[e];
        unsigned int pos = atomicAdd(&lc[r >> 6], 1u);   // LDS atomic only
        // pack: bits[22:17] = local row (r & 63), bits[16:0] = col (< 2^17)
        buf1[pos] = make_int2((int)(((r & 63u) << 17) | (unsigned)cols[e]),
                              __float_as_int(vals[e]));
    }
}

// ---- 5) fused per-bucket counting-sort (LDS) + row-parallel fp16 spmm ----
__global__ __launch_bounds__(512) void finalize_spmm(const unsigned int* __restrict__ bstart,
                                                     const int2* __restrict__ buf1,
                                                     const __half2* __restrict__ embeds_h2,
                                                     float* __restrict__ out) {
    __shared__ unsigned int sedge[CAP];          // (fp16val<<17)|col, row-sorted
    __shared__ unsigned int rstart[RPB + 1];
    __shared__ unsigned int rc[RPB];
    __shared__ unsigned int sscan[RPB];
    const int b = blockIdx.x, t = threadIdx.x;
    const unsigned int S = bstart[b];
    const unsigned int E = bstart[b + 1];
    const unsigned int cnt = E - S;
    const int g   = t >> 5;        // 0..15: 16 groups, 4 rows each
    const int sub = t & 31;        // feature pair; active sub < 24
    const bool act = sub < 24;
    const int row0 = b * RPB;

#define PROC(q)                                                       \
    {                                                                 \
        union { __half h; unsigned short u; } hv;                     \
        hv.u = (unsigned short)((q) >> 17);                           \
        float vv = __half2float(hv.h);                                \
        __half2 e2 = embeds_h2[((q) & 0x1FFFFu) * 24 + sub];          \
        ax = fmaf(vv, __low2float(e2), ax);                           \
        ay = fmaf(vv, __high2float(e2), ay);                          \
    }

    if (cnt <= CAP) {
        if (t < RPB) rc[t] = 0u;
        __syncthreads();
        for (unsigned int j = S + t; j < E; j += 512)
            atomicAdd(&rc[(unsigned)buf1[j].x >> 17], 1u);
        __syncthreads();
        if (t < RPB) sscan[t] = rc[t];
        __syncthreads();
        for (int off = 1; off < RPB; off <<= 1) {
            unsigned int u = 0;
            if (t < RPB && t >= off) u = sscan[t - off];
            __syncthreads();
            if (t < RPB && t >= off) sscan[t] += u;
            __syncthreads();
        }
        if (t < RPB) {
            unsigned int pre = (t == 0) ? 0u : sscan[t - 1];
            rstart[t] = pre;
            rc[t] = pre;   // reuse as LDS scatter cursor
        }
        if (t == 0) rstart[RPB] = cnt;
        __syncthreads();
        for (unsigned int j = S + t; j < E; j += 512) {
            int2 cv = buf1[j];
            unsigned int pos = atomicAdd(&rc[(unsigned)cv.x >> 17], 1u);
            union { __half h; unsigned short u; } hv;
            hv.h = __float2half_rn(__int_as_float(cv.y));  // val>=0 -> 15 bits
            sedge[pos] = ((unsigned int)hv.u << 17) | ((unsigned)cv.x & 0x1FFFFu);
        }
        __syncthreads();

        for (int rr = g * 4; rr < g * 4 + 4; ++rr) {
            int row = row0 + rr;
            if (row >= N_NODES) break;
            unsigned int j = rstart[rr], end = rstart[rr + 1];
            float ax = 0.f, ay = 0.f;
            for (; j + 8 <= end; j += 8) {
                unsigned int q0 = sedge[j + 0];
                unsigned int q1 = sedge[j + 1];
                unsigned int q2 = sedge[j + 2];
                unsigned int q3 = sedge[j + 3];
                unsigned int q4 = sedge[j + 4];
                unsigned int q5 = sedge[j + 5];
                unsigned int q6 = sedge[j + 6];
                unsigned int q7 = sedge[j + 7];
                if (act) {
                    PROC(q0) PROC(q1) PROC(q2) PROC(q3)
                    PROC(q4) PROC(q5) PROC(q6) PROC(q7)
                }
            }
            for (; j < end; ++j) {
                unsigned int q = sedge[j];
                if (act) PROC(q)
            }
            if (act)
                *(float2*)(out + (size_t)row * D_FEAT + sub * 2) = make_float2(ax, ay);
        }
    } else {
        // capacity-overflow fallback (16-sigma event): scan global window
        for (int rr = g * 4; rr < g * 4 + 4; ++rr) {
            int row = row0 + rr;
            if (row >= N_NODES) break;
            float ax = 0.f, ay = 0.f;
            for (unsigned int j = S; j < E; ++j) {
                int2 cv = buf1[j];
                if (((unsigned)cv.x >> 17) == (unsigned)rr && act) {
                    union { __half h; unsigned short u; } hv;
                    hv.h = __float2half_rn(__int_as_float(cv.y));
                    unsigned int q = ((unsigned int)hv.u << 17) | ((unsigned)cv.x & 0x1FFFFu);
                    PROC(q)
                }
            }
            if (act)
                *(float2*)(out + (size_t)row * D_FEAT + sub * 2) = make_float2(ax, ay);
        }
    }
#undef PROC
}

// ---- fallback (tiny ws): edge-parallel global atomics ----
__global__ __launch_bounds__(256) void zero_out_kernel(float4* __restrict__ out, int n4) {
    int i = blockIdx.x * 256 + threadIdx.x;
    if (i < n4) out[i] = make_float4(0.f, 0.f, 0.f, 0.f);
}
__global__ __launch_bounds__(256) void spmm_atomic_kernel(const int* __restrict__ rows,
                                                          const int* __restrict__ cols,
                                                          const float* __restrict__ vals,
                                                          const float* __restrict__ embeds,
                                                          float* __restrict__ out) {
    long long tid = (long long)blockIdx.x * 256 + threadIdx.x;
    const long long total = (long long)N_EDGES * 12;
    if (tid >= total) return;
    int e = (int)(tid / 12), q = (int)(tid % 12);
    int r = rows[e], c = cols[e];
    float v = vals[e];
    const float4 emb = *(const float4*)(embeds + (long long)c * D_FEAT + q * 4);
    float* o = out + (long long)r * D_FEAT + q * 4;
    atomicAdd(o + 0, v * emb.x);
    atomicAdd(o + 1, v * emb.y);
    atomicAdd(o + 2, v * emb.z);
    atomicAdd(o + 3, v * emb.w);
}

extern "C" void kernel_launch(void* const* d_in, const int* in_sizes, int n_in,
                              void* d_out, int out_size, void* d_ws, size_t ws_size,
                              hipStream_t stream) {
    const int*   rows   = (const int*)d_in[0];
    const int*   cols   = (const int*)d_in[1];
    const float* vals   = (const float*)d_in[2];
    const float* embeds = (const float*)d_in[3];
    float*       out    = (float*)d_out;

    // workspace layout (~24 MB):
    //   mat: MAT u32 | bstart: NBUCKETS+1 | bsum: NB_SCAN | buf1: E int2 |
    //   embeds_h: N*48 fp16
    unsigned int* mat = (unsigned int*)d_ws;
    size_t mat_bytes  = ((size_t)MAT * 4 + 15) & ~(size_t)15;
    unsigned int* bstart = (unsigned int*)((char*)d_ws + mat_bytes);
    size_t bs_bytes   = (((size_t)(NBUCKETS + 1) * 4) + 15) & ~(size_t)15;
    unsigned int* bsum = (unsigned int*)((char*)d_ws + mat_bytes + bs_bytes);
    size_t bsum_bytes = (((size_t)NB_SCAN * 4) + 15) & ~(size_t)15;
    int2* buf1 = (int2*)((char*)d_ws + mat_bytes + bs_bytes + bsum_bytes);
    __half2* embeds_h2 = (__half2*)((char*)buf1 + (size_t)N_EDGES * 8);
    size_t need = mat_bytes + bs_bytes + bsum_bytes +
                  (size_t)N_EDGES * 8 + (size_t)N_NODES * D_FEAT * 2;

    if (ws_size < need) {
        int n4 = out_size / 4;
        zero_out_kernel<<<(n4 + 255) / 256, 256, 0, stream>>>((float4*)out, n4);
        long long total = (long long)N_EDGES * 12;
        spmm_atomic_kernel<<<(int)((total + 255) / 256), 256, 0, stream>>>(rows, cols, vals, embeds, out);
        return;
    }

    count_convert<<<NWG + CONV_BLK, 512, 0, stream>>>(rows, mat,
                                                      (const float4*)embeds, embeds_h2);
    scan_phase1<<<NB_SCAN, 256, 0, stream>>>(mat, bsum);
    scan_phase3<<<NB_SCAN, 256, 0, stream>>>(mat, bsum, bstart);
    place_kernel<<<NWG, 512, 0, stream>>>(rows, cols, vals, mat, buf1);
    finalize_spmm<<<NBUCKETS, 512, 0, stream>>>(bstart, buf1, embeds_h2, out);
}

// Round 13
// 83.017 us; speedup vs baseline: 1.2189x; 1.0476x over previous
//
#include <hip/hip_runtime.h>
#include <hip/hip_fp16.h>

// SpMM scatter-reduce: out[r] = sum_{e: rows[e]==r} vals[e] * embeds[cols[e]]
// TWO-KERNEL pipeline (no global scan, no global atomics):
//   A) build_convert (partitioned grid):
//      blocks [0,NWG): chunk-local counting sort. Per WG: LDS histogram of its
//      12500-edge chunk over 1563 buckets -> LDS scan -> write per-chunk bucket
//      offsets mat[w][b] (coalesced row) -> scatter edges bucket-grouped into
//      buf1 within the chunk's own window [w*CHUNK, (w+1)*CHUNK).
//      blocks [NWG,..): embeds fp32 -> fp16.
//   B) finalize_spmm: one 512-thr WG per bucket. Bucket b's edges live in NWG
//      sub-runs (avg 8 edges each); 4 threads per run. Pass1: count rows.
//      Scan(64). Pass2: scatter into row-sorted LDS sedge (packed u32:
//      fp16val<<17|col). Then row-parallel spmm: 16 groups x 32 lanes,
//      4 rows/group, lane = half2 feature pair, x8 gather ILP.

#define N_NODES 100000
#define N_EDGES 1600000
#define D_FEAT  48

#define RPB 64
#define NBUCKETS ((N_NODES + RPB - 1) / RPB)                    // 1563
#define NWG 128
#define CHUNK (N_EDGES / NWG)                                   // 12500 (exact)
#define MROW (NBUCKETS + 1)                                     // 1564
#define CONV_N4 ((N_NODES * D_FEAT) / 4)                        // 1200000
#define CONV_BLK ((CONV_N4 + 511) / 512)                        // 2344
#define CAP 1536   // bucket mean 1024, sd ~32 -> 16 sigma headroom

// ---- A) fused chunk-local counting sort + embeds fp32 -> fp16 ----
__global__ __launch_bounds__(512) void build_convert(const int* __restrict__ rows,
                                                     const int* __restrict__ cols,
                                                     const float* __restrict__ vals,
                                                     unsigned int* __restrict__ mat,
                                                     int2* __restrict__ buf1,
                                                     const float4* __restrict__ esrc,
                                                     __half2* __restrict__ edst) {
    const int t = threadIdx.x;
    if (blockIdx.x < NWG) {
        __shared__ unsigned int hist[NBUCKETS];   // counts -> cursors
        __shared__ unsigned int part[512];
        const int w = blockIdx.x;
        for (int i = t; i < NBUCKETS; i += 512) hist[i] = 0u;
        __syncthreads();
        const int lo = w * CHUNK, hi = lo + CHUNK;
        for (int e = lo + t; e < hi; e += 512)
            atomicAdd(&hist[((unsigned)rows[e]) >> 6], 1u);
        __syncthreads();
        // scan 1563 entries: thread t owns [t*4, t*4+4)
        unsigned int c[4], sum = 0;
#pragma unroll
        for (int k = 0; k < 4; ++k) {
            int idx = t * 4 + k;
            c[k] = (idx < NBUCKETS) ? hist[idx] : 0u;
            sum += c[k];
        }
        part[t] = sum;
        __syncthreads();
        for (int off = 1; off < 512; off <<= 1) {
            unsigned int u = (t >= off) ? part[t - off] : 0u;
            __syncthreads();
            part[t] += u;
            __syncthreads();
        }
        unsigned int pre = (t == 0) ? 0u : part[t - 1];
        unsigned int* mrow = mat + (size_t)w * MROW;
#pragma unroll
        for (int k = 0; k < 4; ++k) {
            int idx = t * 4 + k;
            if (idx < NBUCKETS) {
                mrow[idx] = pre;      // chunk-local bucket start
                hist[idx] = pre;      // reuse as cursor (same thread r/w)
                pre += c[k];
            }
        }
        if (t == 0) mrow[NBUCKETS] = CHUNK;
        __syncthreads();
        for (int e = lo + t; e < hi; e += 512) {
            unsigned r = (unsigned)rows[e];
            unsigned b = r >> 6;
            unsigned pos = (unsigned)lo + atomicAdd(&hist[b], 1u);  // LDS atomic
            // pack: bits[22:17] = local row (r & 63), bits[16:0] = col (< 2^17)
            buf1[pos] = make_int2((int)(((r & 63u) << 17) | (unsigned)cols[e]),
                                  __float_as_int(vals[e]));
        }
    } else {
        int i = (blockIdx.x - NWG) * 512 + t;
        if (i < CONV_N4) {
            float4 v = esrc[i];
            edst[2 * i]     = __floats2half2_rn(v.x, v.y);
            edst[2 * i + 1] = __floats2half2_rn(v.z, v.w);
        }
    }
}

// ---- B) per-bucket gather from sub-runs + row-sort + fp16 spmm ----
__global__ __launch_bounds__(512) void finalize_spmm(const unsigned int* __restrict__ mat,
                                                     const int2* __restrict__ buf1,
                                                     const __half2* __restrict__ embeds_h2,
                                                     float* __restrict__ out) {
    __shared__ unsigned int sedge[CAP];          // (fp16val<<17)|col, row-sorted
    __shared__ unsigned int rstart[RPB + 1];
    __shared__ unsigned int rc[RPB];
    __shared__ unsigned int sscan[RPB];
    const int b = blockIdx.x, t = threadIdx.x;
    const int run  = t >> 2;                     // 0..127
    const int sub4 = t & 3;
    // run bounds (4 threads/run broadcast the same 8B pair)
    const unsigned int* mr = mat + (size_t)run * MROW + b;
    const unsigned int s  = mr[0];
    const unsigned int e2 = mr[1];
    const unsigned int base = (unsigned)run * CHUNK;
    const int g   = t >> 5;        // 0..15: 16 groups, 4 rows each
    const int sub = t & 31;        // feature pair; active sub < 24
    const bool act = sub < 24;
    const int row0 = b * RPB;

#define PROC(q)                                                       \
    {                                                                 \
        union { __half h; unsigned short u; } hv;                     \
        hv.u = (unsigned short)((q) >> 17);                           \
        float vv = __half2float(hv.h);                                \
        __half2 e2v = embeds_h2[((q) & 0x1FFFFu) * 24 + sub];         \
        ax = fmaf(vv, __low2float(e2v), ax);                          \
        ay = fmaf(vv, __high2float(e2v), ay);                         \
    }

    if (t < RPB) rc[t] = 0u;
    __syncthreads();
    // pass 1: count rows
    for (unsigned int k = s + sub4; k < e2; k += 4)
        atomicAdd(&rc[(unsigned)buf1[base + k].x >> 17], 1u);
    __syncthreads();
    // scan 64 counts
    if (t < RPB) sscan[t] = rc[t];
    __syncthreads();
    for (int off = 1; off < RPB; off <<= 1) {
        unsigned int u = 0;
        if (t < RPB && t >= off) u = sscan[t - off];
        __syncthreads();
        if (t < RPB && t >= off) sscan[t] += u;
        __syncthreads();
    }
    if (t < RPB) {
        unsigned int pre = (t == 0) ? 0u : sscan[t - 1];
        rstart[t] = pre;
        rc[t] = pre;   // reuse as scatter cursor
    }
    if (t == 0) rstart[RPB] = sscan[RPB - 1];
    __syncthreads();
    const unsigned int cnt = rstart[RPB];

    if (cnt <= CAP) {
        // pass 2: scatter into row-sorted LDS
        for (unsigned int k = s + sub4; k < e2; k += 4) {
            int2 cv = buf1[base + k];
            unsigned int pos = atomicAdd(&rc[(unsigned)cv.x >> 17], 1u);
            union { __half h; unsigned short u; } hv;
            hv.h = __float2half_rn(__int_as_float(cv.y));  // val>=0 -> 15 bits
            sedge[pos] = ((unsigned int)hv.u << 17) | ((unsigned)cv.x & 0x1FFFFu);
        }
        __syncthreads();

        for (int rr = g * 4; rr < g * 4 + 4; ++rr) {
            int row = row0 + rr;
            if (row >= N_NODES) break;
            unsigned int j = rstart[rr], end = rstart[rr + 1];
            float ax = 0.f, ay = 0.f;
            for (; j + 8 <= end; j += 8) {
                unsigned int q0 = sedge[j + 0];
                unsigned int q1 = sedge[j + 1];
                unsigned int q2 = sedge[j + 2];
                unsigned int q3 = sedge[j + 3];
                unsigned int q4 = sedge[j + 4];
                unsigned int q5 = sedge[j + 5];
                unsigned int q6 = sedge[j + 6];
                unsigned int q7 = sedge[j + 7];
                if (act) {
                    PROC(q0) PROC(q1) PROC(q2) PROC(q3)
                    PROC(q4) PROC(q5) PROC(q6) PROC(q7)
                }
            }
            for (; j < end; ++j) {
                unsigned int q = sedge[j];
                if (act) PROC(q)
            }
            if (act)
                *(float2*)(out + (size_t)row * D_FEAT + sub * 2) = make_float2(ax, ay);
        }
    } else {
        // capacity-overflow fallback (16-sigma event): filter-scan all runs
        for (int rr = g * 4; rr < g * 4 + 4; ++rr) {
            int row = row0 + rr;
            if (row >= N_NODES) break;
            float ax = 0.f, ay = 0.f;
            for (int i = 0; i < NWG; ++i) {
                const unsigned int* mri = mat + (size_t)i * MROW + b;
                unsigned int si = mri[0], ei = mri[1];
                for (unsigned int k = si; k < ei; ++k) {
                    int2 cv = buf1[(unsigned)i * CHUNK + k];
                    if (((unsigned)cv.x >> 17) == (unsigned)rr && act) {
                        union { __half h; unsigned short u; } hv;
                        hv.h = __float2half_rn(__int_as_float(cv.y));
                        unsigned int q = ((unsigned int)hv.u << 17) | ((unsigned)cv.x & 0x1FFFFu);
                        PROC(q)
                    }
                }
            }
            if (act)
                *(float2*)(out + (size_t)row * D_FEAT + sub * 2) = make_float2(ax, ay);
        }
    }
#undef PROC
}

// ---- fallback (tiny ws): edge-parallel global atomics ----
__global__ __launch_bounds__(256) void zero_out_kernel(float4* __restrict__ out, int n4) {
    int i = blockIdx.x * 256 + threadIdx.x;
    if (i < n4) out[i] = make_float4(0.f, 0.f, 0.f, 0.f);
}
__global__ __launch_bounds__(256) void spmm_atomic_kernel(const int* __restrict__ rows,
                                                          const int* __restrict__ cols,
                                                          const float* __restrict__ vals,
                                                          const float* __restrict__ embeds,
                                                          float* __restrict__ out) {
    long long tid = (long long)blockIdx.x * 256 + threadIdx.x;
    const long long total = (long long)N_EDGES * 12;
    if (tid >= total) return;
    int e = (int)(tid / 12), q = (int)(tid % 12);
    int r = rows[e], c = cols[e];
    float v = vals[e];
    const float4 emb = *(const float4*)(embeds + (long long)c * D_FEAT + q * 4);
    float* o = out + (long long)r * D_FEAT + q * 4;
    atomicAdd(o + 0, v * emb.x);
    atomicAdd(o + 1, v * emb.y);
    atomicAdd(o + 2, v * emb.z);
    atomicAdd(o + 3, v * emb.w);
}

extern "C" void kernel_launch(void* const* d_in, const int* in_sizes, int n_in,
                              void* d_out, int out_size, void* d_ws, size_t ws_size,
                              hipStream_t stream) {
    const int*   rows   = (const int*)d_in[0];
    const int*   cols   = (const int*)d_in[1];
    const float* vals   = (const float*)d_in[2];
    const float* embeds = (const float*)d_in[3];
    float*       out    = (float*)d_out;

    // workspace layout (~23.2 MB):
    //   mat: NWG*MROW u32 (chunk-local bucket offsets) | buf1: E int2 |
    //   embeds_h: N*48 fp16
    unsigned int* mat = (unsigned int*)d_ws;
    size_t mat_bytes  = ((size_t)NWG * MROW * 4 + 15) & ~(size_t)15;
    int2* buf1 = (int2*)((char*)d_ws + mat_bytes);
    __half2* embeds_h2 = (__half2*)((char*)buf1 + (size_t)N_EDGES * 8);
    size_t need = mat_bytes + (size_t)N_EDGES * 8 + (size_t)N_NODES * D_FEAT * 2;

    if (ws_size < need) {
        int n4 = out_size / 4;
        zero_out_kernel<<<(n4 + 255) / 256, 256, 0, stream>>>((float4*)out, n4);
        long long total = (long long)N_EDGES * 12;
        spmm_atomic_kernel<<<(int)((total + 255) / 256), 256, 0, stream>>>(rows, cols, vals, embeds, out);
        return;
    }

    build_convert<<<NWG + CONV_BLK, 512, 0, stream>>>(rows, cols, vals, mat, buf1,
                                                      (const float4*)embeds, embeds_h2);
    finalize_spmm<<<NBUCKETS, 512, 0, stream>>>(mat, buf1, embeds_h2, out);
}